// Round 11
// baseline (406.804 us; speedup 1.0000x reference)
//
#include <hip/hip_runtime.h>
#include <hip/hip_bf16.h>

#define LL 80
#define NPIX 784
#define PBATCH 15680

#define DI __device__ __forceinline__

typedef short s8v __attribute__((ext_vector_type(8)));     // 8 bf16 = 16B
typedef short short4v __attribute__((ext_vector_type(4))); // 4 bf16 = 8B
typedef float f32x4 __attribute__((ext_vector_type(4)));   // MFMA acc

DI float b2f(__hip_bfloat16 x) { return __bfloat162float(x); }
DI float s2f(short h) { return __uint_as_float(((unsigned int)(unsigned short)h) << 16); }

// f32 -> bf16 bits, round-nearest-even
DI short f2b(float x) {
    unsigned int b = __float_as_uint(x);
    b += 0x7fffu + ((b >> 16) & 1u);
    return (short)(b >> 16);
}

// F=1: buffer holds f32; F=0: buffer holds bf16
template <int F> DI float LD(const void* p, int i) {
    if (F) return ((const float*)p)[i];
    return b2f(((const __hip_bfloat16*)p)[i]);
}
DI float LDf(int f, const void* p, int i) { return f ? ((const float*)p)[i] : b2f(((const __hip_bfloat16*)p)[i]); }

DI float fast_tanh(float x) {
    float e = __expf(2.0f * x);
    return 1.0f - 2.0f / (e + 1.0f);
}
DI float fast_sigmoid(float x) { return 1.0f / (1.0f + __expf(-x)); }

// ---------------- dtype probe (proven R3-R10) ----------------
__global__ __launch_bounds__(256) void detect_dtype(const void* probe, int n, int* flag) {
    __shared__ int bad;
    if (threadIdx.x == 0) bad = 0;
    __syncthreads();
    int c = 0;
    for (int i = threadIdx.x; i < n; i += 256) {
        float v = b2f(((const __hip_bfloat16*)probe)[i]);
        if (!(fabsf(v) < 1000.0f)) c++;
    }
    if (c) atomicAdd(&bad, c);
    __syncthreads();
    if (threadIdx.x == 0) *flag = (bad > 8) ? 1 : 0;   // 1 => inputs are f32
}

// ---------------- prep sub-parts ----------------
DI void cvt_part(int f, const void* src, short* __restrict__ dst, int blk, int n) {
    int i0 = (blk * 256 + threadIdx.x) * 4;
    if (i0 >= n) return;
    if (f) {
        float4 v = *(const float4*)((const float*)src + i0);
        short4v o = { f2b(v.x), f2b(v.y), f2b(v.z), f2b(v.w) };
        *(short4v*)(dst + i0) = o;
    } else {
        *(short4v*)(dst + i0) = *(const short4v*)((const short*)src + i0);
    }
}

// wcat[4096][1024]: rows 0-1023 w3 folded, 1024-2047 w4 folded, 2048-3071 w5 folded, 3072-4095 u3
DI void wcat_part(int f, const void* w3, const void* w4, const void* w5, const void* u3,
                  short* __restrict__ wcat, int blk) {
    int i0 = (blk * 256 + threadIdx.x) * 4;
    int nr = i0 >> 10, k = i0 & 1023;
    int j = nr >> 10, r = nr & 1023;
    const void* W = (j == 0) ? w3 : (j == 1) ? w4 : (j == 2) ? w5 : u3;
    float4 v;
    if (j < 3) {
        if (f) {
            float4 x = *(const float4*)((const float*)W + r * 2048 + k);
            float4 y = *(const float4*)((const float*)W + r * 2048 + 1024 + k);
            v.x = x.x + y.x; v.y = x.y + y.y; v.z = x.z + y.z; v.w = x.w + y.w;
        } else {
            const short* Ws = (const short*)W;
            short4v x = *(const short4v*)(Ws + r * 2048 + k);
            short4v y = *(const short4v*)(Ws + r * 2048 + 1024 + k);
            v.x = s2f(x.x) + s2f(y.x); v.y = s2f(x.y) + s2f(y.y);
            v.z = s2f(x.z) + s2f(y.z); v.w = s2f(x.w) + s2f(y.w);
        }
    } else {
        if (f) v = *(const float4*)((const float*)W + r * 1024 + k);
        else {
            short4v x = *(const short4v*)((const short*)W + r * 1024 + k);
            v.x = s2f(x.x); v.y = s2f(x.y); v.z = s2f(x.z); v.w = s2f(x.w);
        }
    }
    short4v o = { f2b(v.x), f2b(v.y), f2b(v.z), f2b(v.w) };
    *(short4v*)(wcat + i0) = o;
}

// u partial: 64 splits x 16 j each
template <int F>
DI void u_part(const void* fc3_w, const void* fca_w, float* __restrict__ uP, int jsplit) {
    int k4 = threadIdx.x * 4;
    float4 acc = {0.f, 0.f, 0.f, 0.f};
    for (int j = jsplit * 16; j < jsplit * 16 + 16; j++) {
        float fa = LD<F>(fca_w, j);
        float4 row;
        if (F) row = *(const float4*)((const float*)fc3_w + j * 1024 + k4);
        else {
            short4v x = *(const short4v*)((const short*)fc3_w + j * 1024 + k4);
            row.x = s2f(x.x); row.y = s2f(x.y); row.z = s2f(x.z); row.w = s2f(x.w);
        }
        acc.x += fa * row.x; acc.y += fa * row.y;
        acc.z += fa * row.z; acc.w += fa * row.w;
    }
    *(float4*)(uP + jsplit * 1024 + k4) = acc;
}

template <int F>
DI void c0_part(const void* fc3_b, const void* fca_w, const void* fca_b,
                float* c0, float* red) {
    float acc = 0.f;
    for (int j = threadIdx.x; j < 1024; j += 256)
        acc += LD<F>(fc3_b, j) * LD<F>(fca_w, j);
    red[threadIdx.x] = acc;
    __syncthreads();
    for (int s = 128; s > 0; s >>= 1) {
        if (threadIdx.x < s) red[threadIdx.x] += red[threadIdx.x + s];
        __syncthreads();
    }
    if (threadIdx.x == 0) *c0 = red[0] + LD<F>(fca_b, 0);
}

// SIMT GEMM for tiny fc2 (M=80,N=1024,K=300), k-split to [kb,ke), lds = 2176 floats
template <int F>
DI void fc2_part(float* lds, const void* word, const void* fc2_w, float* C,
                 int bx, int by, int kb, int ke) {
    float* As = lds;            // [16][68]
    float* Ws2 = lds + 1088;    // [16][68]
    const int tid = threadIdx.x;
    const int tx = tid & 15, ty = tid >> 4;
    const int m0 = by * 64, n0 = bx * 64;
    const int M = 80;
    float acc[4][4] = {};

    for (int k0 = kb; k0 < ke; k0 += 16) {
#pragma unroll
        for (int i = 0; i < 4; i++) {
            int idx = tid + i * 256;
            int kk = idx & 15, mm = idx >> 4;
            int m = m0 + mm, k = k0 + kk;
            As[kk * 68 + mm] = (m < M && k < ke) ? LD<F>(word, m * 300 + k) : 0.f;
        }
#pragma unroll
        for (int i = 0; i < 4; i++) {
            int idx = tid + i * 256;
            int kk = idx & 15, nn = idx >> 4;
            int n = n0 + nn, k = k0 + kk;
            Ws2[kk * 68 + nn] = (k < ke) ? LD<F>(fc2_w, n * 300 + k) : 0.f;
        }
        __syncthreads();
#pragma unroll
        for (int kk = 0; kk < 16; kk++) {
            float4 av = *(const float4*)(&As[kk * 68 + ty * 4]);
            float4 wv = *(const float4*)(&Ws2[kk * 68 + tx * 4]);
            float a4[4] = {av.x, av.y, av.z, av.w};
            float w4[4] = {wv.x, wv.y, wv.z, wv.w};
#pragma unroll
            for (int i = 0; i < 4; i++)
#pragma unroll
                for (int j = 0; j < 4; j++)
                    acc[i][j] += a4[i] * w4[j];
        }
        __syncthreads();
    }

    for (int i = 0; i < 4; i++) {
        int m = m0 + ty * 4 + i;
        if (m >= M) continue;
        for (int j = 0; j < 4; j++)
            C[m * 1024 + n0 + tx * 4 + j] = acc[i][j];
    }
}

// ONE dispatch for all independent prep; all sub-jobs have short serial depth.
__global__ __launch_bounds__(256) void mega_prep(
    const int* flag,
    const void* fmap, const void* fc1_w, const void* u5w, const void* fco_w,
    const void* w3, const void* w4, const void* w5, const void* u3,
    const void* fc3_w, const void* fc3_b, const void* fca_w, const void* fca_b,
    const void* word, const void* fc2_w,
    short* fmap_b, short* fc1w_b, short* u5w_b, short* wcat_b, short* fcow_b,
    float* uP, float* c0, float* f_wdP) {
    __shared__ float lds[2176];
    int f = *flag;
    int bid = blockIdx.x;
    if (bid < 64) {
        if (f) u_part<1>(fc3_w, fca_w, uP, bid);
        else   u_part<0>(fc3_w, fca_w, uP, bid);
    } else if (bid == 64) {
        if (f) c0_part<1>(fc3_b, fca_w, fca_b, c0, lds);
        else   c0_part<0>(fc3_b, fca_w, fca_b, c0, lds);
    } else if (bid < 193) {
        int r = bid - 65;
        int sp = r >> 5, rr = r & 31;
        int kb = sp * 80, ke = (sp == 3) ? 300 : kb + 80;
        float* C = f_wdP + sp * 81920;
        if (f) fc2_part<1>(lds, word, fc2_w, C, rr & 15, rr >> 4, kb, ke);
        else   fc2_part<0>(lds, word, fc2_w, C, rr & 15, rr >> 4, kb, ke);
    }
    else if (bid < 977)  cvt_part(f, fmap,  fmap_b, bid - 193,  802816);
    else if (bid < 2001) cvt_part(f, fc1_w, fc1w_b, bid - 977,  1048576);
    else if (bid < 3025) cvt_part(f, u5w,   u5w_b,  bid - 2001, 1048576);
    else if (bid < 7121) wcat_part(f, w3, w4, w5, u3, wcat_b, bid - 3025);
    else                 cvt_part(f, fco_w, fcow_b, bid - 7121, 4194304);
}

// reduce uP[64][1024] -> u, f_wdP[4][81920] -> f_wd
__global__ __launch_bounds__(256) void reduce_pre(
    const float* __restrict__ uP, const float* __restrict__ f_wdP,
    float* __restrict__ u, float* __restrict__ f_wd) {
    if (blockIdx.x < 80) {
        int i4 = (blockIdx.x * 256 + threadIdx.x) * 4;
        float4 a = *(const float4*)(f_wdP + i4);
        float4 b = *(const float4*)(f_wdP + 81920 + i4);
        float4 c = *(const float4*)(f_wdP + 163840 + i4);
        float4 d = *(const float4*)(f_wdP + 245760 + i4);
        float4 o = {a.x+b.x+c.x+d.x, a.y+b.y+c.y+d.y, a.z+b.z+c.z+d.z, a.w+b.w+c.w+d.w};
        *(float4*)(f_wd + i4) = o;
    } else {
        int k4 = threadIdx.x * 4;
        float4 acc = {0.f, 0.f, 0.f, 0.f};
        for (int p = 0; p < 64; p++) {
            float4 q = *(const float4*)(uP + p * 1024 + k4);
            acc.x += q.x; acc.y += q.y; acc.z += q.z; acc.w += q.w;
        }
        *(float4*)(u + k4) = acc;
    }
}

// ================= bf16 MFMA GEMM core — software-pipelined (proven R10) =================
DI void mcore_b(const short* __restrict__ A, int lda,
                const short* __restrict__ B, int ldb,
                float* __restrict__ C, int ldc,
                int M, int kb, int ke, int m0, int n0) {
    __shared__ short As[4][64][8];
    __shared__ short Ws[4][64][8];
    const int tid = threadIdx.x;
    const int wv = tid >> 6, lane = tid & 63;
    const int mA = tid & 63, qA = tid >> 6;
    const int gm = m0 + mA;
    const int lp = (mA & 15) | (qA << 4), lg = mA >> 4;
    f32x4 acc[4] = {};

    s8v va = {0,0,0,0,0,0,0,0};
    if (gm < M) va = *(const s8v*)(A + gm * lda + kb + 8 * qA);
    s8v vb = *(const s8v*)(B + (n0 + mA) * ldb + kb + 8 * qA);

    for (int k0 = kb; k0 < ke; k0 += 32) {
        *(s8v*)&As[lg][lp][0] = va;
        *(s8v*)&Ws[lg][lp][0] = vb;
        __syncthreads();
        int kn = k0 + 32;
        if (kn < ke) {
            if (gm < M) va = *(const s8v*)(A + gm * lda + kn + 8 * qA);
            vb = *(const s8v*)(B + (n0 + mA) * ldb + kn + 8 * qA);
        }
        s8v af = *(const s8v*)&As[wv][lane][0];
#pragma unroll
        for (int nf = 0; nf < 4; nf++) {
            s8v bf = *(const s8v*)&Ws[nf][lane][0];
            acc[nf] = __builtin_amdgcn_mfma_f32_16x16x32_bf16(af, bf, acc[nf], 0, 0, 0);
        }
        __syncthreads();
    }

    const int q = lane >> 4, cc = lane & 15;
#pragma unroll
    for (int nf = 0; nf < 4; nf++) {
        int n = n0 + 16 * nf + cc;
#pragma unroll
        for (int r = 0; r < 4; r++) {
            int m = m0 + 16 * wv + q * 4 + r;
            if (m < M) C[m * ldc + n] = acc[nf][r];
        }
    }
}

// fc1: no k-split (R10: pipelined K-loop is latency-cheap) — single fh buffer
__global__ __launch_bounds__(256) void mfma_fc1(
    const short* __restrict__ fmap_b, const short* __restrict__ fc1w_b,
    float* __restrict__ fh) {
    mcore_b(fmap_b, 1024, fc1w_b, 1024, fh, 1024,
            NPIX, 0, 1024, blockIdx.y * 64, blockIdx.x * 64);
}

// gate: no k-split — single gP[320][4096]
__global__ __launch_bounds__(256) void mfma_gate(
    const short* __restrict__ a_b, const short* __restrict__ nodes_b,
    const short* __restrict__ wcat_b, float* __restrict__ gP) {
    const short* A = (blockIdx.x >= 48) ? nodes_b : a_b;
    mcore_b(A, 1024, wcat_b, 1024, gP, 4096,
            320, 0, 1024, blockIdx.y * 64, blockIdx.x * 64);
}

// u5 GEMM with FUSED ew_upd epilogue, pipelined (K=1024), single-gP reads.
__global__ __launch_bounds__(256) void mfma_u5f(
    const int* flag, const short* __restrict__ rn_b, const short* __restrict__ u5w_b,
    const float* __restrict__ gP,
    const void* b3, const void* u3b, const void* b5, const void* u5b,
    float* __restrict__ nodes, short* __restrict__ nodes_b) {
    __shared__ short As[4][64][8];
    __shared__ short Ws[4][64][8];
    const int tid = threadIdx.x;
    const int wv = tid >> 6, lane = tid & 63;
    const int mA = tid & 63, qA = tid >> 6;
    const int lp = (mA & 15) | (qA << 4), lg = mA >> 4;
    const int m0 = blockIdx.y * 64, n0 = blockIdx.x * 64;
    f32x4 acc[4] = {};

    s8v va = *(const s8v*)(rn_b + (m0 + mA) * 1024 + 8 * qA);
    s8v vb = *(const s8v*)(u5w_b + (n0 + mA) * 1024 + 8 * qA);

    for (int k0 = 0; k0 < 1024; k0 += 32) {
        *(s8v*)&As[lg][lp][0] = va;
        *(s8v*)&Ws[lg][lp][0] = vb;
        __syncthreads();
        int kn = k0 + 32;
        if (kn < 1024) {
            va = *(const s8v*)(rn_b + (m0 + mA) * 1024 + kn + 8 * qA);
            vb = *(const s8v*)(u5w_b + (n0 + mA) * 1024 + kn + 8 * qA);
        }
        s8v af = *(const s8v*)&As[wv][lane][0];
#pragma unroll
        for (int nf = 0; nf < 4; nf++) {
            s8v bf = *(const s8v*)&Ws[nf][lane][0];
            acc[nf] = __builtin_amdgcn_mfma_f32_16x16x32_bf16(af, bf, acc[nf], 0, 0, 0);
        }
        __syncthreads();
    }

    const int f = *flag;
    const int q = lane >> 4, cc = lane & 15;
#pragma unroll
    for (int nf = 0; nf < 4; nf++) {
        int n = n0 + 16 * nf + cc;
        float bb3 = LDf(f, b3, n), bu3 = LDf(f, u3b, n);
        float bb5 = LDf(f, b5, n), bu5 = LDf(f, u5b, n);
#pragma unroll
        for (int r = 0; r < 4; r++) {
            int m = m0 + 16 * wv + q * 4 + r;
            int i = m * 1024 + n, base = m * 4096;
            float az = gP[base + n];
            float ah = gP[base + 2048 + n];
            float ux = gP[base + 3072 + n];
            float z = fast_sigmoid(az + ux + bb3 + bu3);
            float h = fast_tanh(ah + acc[nf][r] + bb5 + bu5);
            float nd = (1.f - z) * nodes[i] + z * h;
            nodes[i] = nd;
            nodes_b[i] = f2b(nd);
        }
    }
}

// final GEMM with FUSED bias+tanh+store, pipelined (K=2048, A switches at 1024).
__global__ __launch_bounds__(256) void mfma_finf(
    const int* flag, const short* __restrict__ nodes_b, const short* __restrict__ g_b,
    const short* __restrict__ fcow_b, const void* fco_b, void* out) {
    __shared__ short As[4][64][8];
    __shared__ short Ws[4][64][8];
    const int tid = threadIdx.x;
    const int wv = tid >> 6, lane = tid & 63;
    const int mA = tid & 63, qA = tid >> 6;
    const int lp = (mA & 15) | (qA << 4), lg = mA >> 4;
    const int m0 = blockIdx.y * 64, n0 = blockIdx.x * 64;
    f32x4 acc[4] = {};

    s8v va = *(const s8v*)(nodes_b + (m0 + mA) * 1024 + 8 * qA);
    s8v vb = *(const s8v*)(fcow_b + (n0 + mA) * 2048 + 8 * qA);

    for (int k0 = 0; k0 < 2048; k0 += 32) {
        *(s8v*)&As[lg][lp][0] = va;
        *(s8v*)&Ws[lg][lp][0] = vb;
        __syncthreads();
        int kn = k0 + 32;
        if (kn < 2048) {
            const short* Apn = (kn < 1024) ? nodes_b : (g_b - 1024);
            va = *(const s8v*)(Apn + (m0 + mA) * 1024 + kn + 8 * qA);
            vb = *(const s8v*)(fcow_b + (n0 + mA) * 2048 + kn + 8 * qA);
        }
        s8v af = *(const s8v*)&As[wv][lane][0];
#pragma unroll
        for (int nf = 0; nf < 4; nf++) {
            s8v bf = *(const s8v*)&Ws[nf][lane][0];
            acc[nf] = __builtin_amdgcn_mfma_f32_16x16x32_bf16(af, bf, acc[nf], 0, 0, 0);
        }
        __syncthreads();
    }

    const int f = *flag;
    const int q = lane >> 4, cc = lane & 15;
#pragma unroll
    for (int nf = 0; nf < 4; nf++) {
        int n = n0 + 16 * nf + cc;
        float bias = LDf(f, fco_b, n);
#pragma unroll
        for (int r = 0; r < 4; r++) {
            int m = m0 + 16 * wv + q * 4 + r;
            float v = fast_tanh(acc[nf][r] + bias);
            if (f) ((float*)out)[m * 2048 + n] = v;
            else   ((__hip_bfloat16*)out)[m * 2048 + n] = __float2bfloat16(v);
        }
    }
}

// ---------------- coeff: float4, grid (784,4) — R10 was grid-occupancy-limited ----------------
__global__ __launch_bounds__(256) void coeff_kernel(
    const float* __restrict__ fh, const float* __restrict__ f_wd,
    const float* __restrict__ u, const float* __restrict__ c0p,
    float* __restrict__ s) {
    int n = blockIdx.x;  // 0..783
    __shared__ float4 fh4[256];
    __shared__ float4 uu4[256];
    int t = threadIdx.x;
    {
        fh4[t] = *(const float4*)(fh + n * 1024 + t * 4);
        uu4[t] = *(const float4*)(u + t * 4);
    }
    __syncthreads();
    float c0 = *c0p;
    int wave = t >> 6, lane = t & 63;
    int b = n / 196, hw = n % 196;
    int l0 = blockIdx.y * 20;
    for (int l = l0 + wave; l < l0 + 20; l += 4) {
        const float4* fd4 = (const float4*)(f_wd + l * 1024);
        float p = 0.f;
#pragma unroll
        for (int k = 0; k < 4; k++) {
            int idx = lane + k * 64;
            float4 h = fh4[idx];
            float4 d = fd4[idx];
            float4 uu = uu4[idx];
            p += fast_tanh(h.x * d.x) * uu.x;
            p += fast_tanh(h.y * d.y) * uu.y;
            p += fast_tanh(h.z * d.z) * uu.z;
            p += fast_tanh(h.w * d.w) * uu.w;
        }
        for (int off = 32; off > 0; off >>= 1) p += __shfl_down(p, off);
        if (lane == 0) s[b * PBATCH + hw * LL + l] = p + c0;
    }
}

// ---------------- softmax over contiguous 196-chunks ----------------
__global__ __launch_bounds__(64) void softmax196(float* __restrict__ s) {
    float* p = s + blockIdx.x * 196;
    int lane = threadIdx.x;
    float v[4];
    float mx = -1e30f;
#pragma unroll
    for (int i = 0; i < 4; i++) {
        int idx = lane + i * 64;
        v[i] = (idx < 196) ? p[idx] : -1e30f;
        mx = fmaxf(mx, v[i]);
    }
    for (int off = 32; off > 0; off >>= 1) mx = fmaxf(mx, __shfl_down(mx, off));
    mx = __shfl(mx, 0);
    float sum = 0.f;
#pragma unroll
    for (int i = 0; i < 4; i++) {
        int idx = lane + i * 64;
        if (idx < 196) { v[i] = __expf(v[i] - mx); sum += v[i]; }
    }
    for (int off = 32; off > 0; off >>= 1) sum += __shfl_down(sum, off);
    sum = __shfl(sum, 0);
    float inv = 1.f / sum;
#pragma unroll
    for (int i = 0; i < 4; i++) {
        int idx = lane + i * 64;
        if (idx < 196) p[idx] = v[i] * inv;
    }
}

// ---------------- g: reads bf16 fmap_b, 4 c per thread ----------------
__global__ __launch_bounds__(256) void g_kernel(
    const float* __restrict__ s, const short* __restrict__ fmap_b,
    float* __restrict__ nodes, short* __restrict__ nodes_b, short* __restrict__ g_b) {
    int bl = blockIdx.x;
    int b = bl / LL, l = bl % LL;
    __shared__ float co[196];
    for (int i = threadIdx.x; i < 196; i += 256)
        co[i] = s[b * PBATCH + i * LL + l];
    __syncthreads();
    int c4 = threadIdx.x * 4;
    const short* base = fmap_b + b * 196 * 1024 + c4;
    float a0 = 0.f, a1 = 0.f, a2 = 0.f, a3 = 0.f;
    for (int hw = 0; hw < 196; hw++) {
        short4v v = *(const short4v*)(base + hw * 1024);
        float w = co[hw];
        a0 += w * s2f(v.x); a1 += w * s2f(v.y);
        a2 += w * s2f(v.z); a3 += w * s2f(v.w);
    }
    int o = bl * 1024 + c4;
    float4 fa = {a0, a1, a2, a3};
    *(float4*)(nodes + o) = fa;
    short4v bb = { f2b(a0), f2b(a1), f2b(a2), f2b(a3) };
    *(short4v*)(nodes_b + o) = bb;
    *(short4v*)(g_b + o) = bb;
}

// ---------------- adj: 4 c per thread ----------------
template <int F>
DI void adj_core(float* arw, const void* adj, const float* nodes, short* a_b) {
    int bl = blockIdx.x;
    int b = bl / LL, l = bl % LL;
    if (threadIdx.x < LL) arw[threadIdx.x] = LD<F>(adj, l * LL + threadIdx.x);
    __syncthreads();
    int c4 = threadIdx.x * 4;
    const float* nb = nodes + b * LL * 1024 + c4;
    float a0 = 0.f, a1 = 0.f, a2 = 0.f, a3 = 0.f;
    for (int m = 0; m < LL; m++) {
        float am = arw[m];
        float4 nd = *(const float4*)(nb + m * 1024);
        a0 += am * nd.x; a1 += am * nd.y; a2 += am * nd.z; a3 += am * nd.w;
    }
    short4v bb = { f2b(a0), f2b(a1), f2b(a2), f2b(a3) };
    *(short4v*)(a_b + bl * 1024 + c4) = bb;
}

__global__ __launch_bounds__(256) void adj_kernel(
    const int* flag, const void* adj, const float* nodes, short* a_b) {
    __shared__ float arw[LL];
    if (*flag) adj_core<1>(arw, adj, nodes, a_b);
    else       adj_core<0>(arw, adj, nodes, a_b);
}

// ---------------- rn_b = bf16( sigmoid(ar + u3x + b4 + u3b) * nodes ), x4, single gP ----------------
template <int F>
DI void ew_r_core(const float* gP, const float* nodes,
                  const void* b4, const void* u3b, short* rn_b, int i4) {
    int m = i4 >> 10, c = i4 & 1023;
    int base = m * 4096;
    float4 r0 = *(const float4*)(gP + base + 1024 + c);
    float4 x0 = *(const float4*)(gP + base + 3072 + c);
    float4 nd = *(const float4*)(nodes + i4);
    short4v o;
    o.x = f2b(fast_sigmoid(r0.x + x0.x + LD<F>(b4, c)   + LD<F>(u3b, c))   * nd.x);
    o.y = f2b(fast_sigmoid(r0.y + x0.y + LD<F>(b4, c+1) + LD<F>(u3b, c+1)) * nd.y);
    o.z = f2b(fast_sigmoid(r0.z + x0.z + LD<F>(b4, c+2) + LD<F>(u3b, c+2)) * nd.z);
    o.w = f2b(fast_sigmoid(r0.w + x0.w + LD<F>(b4, c+3) + LD<F>(u3b, c+3)) * nd.w);
    *(short4v*)(rn_b + i4) = o;
}

__global__ void ew_r(const int* flag, const float* gP, const float* nodes,
                     const void* b4, const void* u3b, short* rn_b, int n) {
    int i4 = (blockIdx.x * 256 + threadIdx.x) * 4;
    if (i4 >= n) return;
    if (*flag) ew_r_core<1>(gP, nodes, b4, u3b, rn_b, i4);
    else       ew_r_core<0>(gP, nodes, b4, u3b, rn_b, i4);
}

extern "C" void kernel_launch(void* const* d_in, const int* in_sizes, int n_in,
                              void* d_out, int out_size, void* d_ws, size_t ws_size,
                              hipStream_t stream) {
    const void* fmap  = d_in[0];
    const void* word  = d_in[1];
    const void* adjm  = d_in[2];
    const void* fc1_w = d_in[3];
    const void* fc2_w = d_in[4];
    const void* fc3_w = d_in[5];
    const void* fc3_b = d_in[6];
    const void* fca_w = d_in[7];
    const void* fca_b = d_in[8];
    const void* w3    = d_in[9];
    const void* b3    = d_in[10];
    const void* u3    = d_in[11];
    const void* u3b   = d_in[12];
    const void* w4    = d_in[13];
    const void* b4    = d_in[14];
    const void* w5    = d_in[15];
    const void* b5    = d_in[16];
    const void* u5    = d_in[17];
    const void* u5b   = d_in[18];
    const void* fco_w = d_in[19];
    const void* fco_b = d_in[20];

    // ---- workspace: increments in FLOATS (bf16 buffers = elems/2). ~31.9 MB.
    int*   flag    = (int*)d_ws;
    float* P       = (float*)d_ws + 16;
    float* nodes   = P;                       P += 327680;   // f32, persistent
    short* nodes_b = (short*)P;               P += 163840;   // 327680 bf16
    short* g_b     = (short*)P;               P += 163840;   // 327680 bf16
    short* a_b     = (short*)P;               P += 163840;   // 327680 bf16
    short* rn_b    = (short*)P;               P += 163840;   // 327680 bf16
    short* u5w_b   = (short*)P;               P += 524288;   // 1048576 bf16
    short* wcat_b  = (short*)P;               P += 2097152;  // 4194304 bf16
    float* R       = P;                                      // overlay region
    // semantic phase (2,267,408 f)
    float* fh     = R;                            // 802816 (single, no split)
    float* f_wd   = R + 802816;                   // 81920
    float* f_wdP  = f_wd + 81920;                 // 4 x 81920
    float* uP     = f_wdP + 327680;               // 64 x 1024 partials
    float* u      = uP + 65536;                   // 1024
    float* c0     = u + 1024;                     // 16
    float* s      = c0 + 16;                      // 62720
    short* fmap_b = (short*)(s + 62720);          // 802816 shorts = 401408 f
    short* fc1w_b = (short*)(s + 62720 + 401408); // 1048576 shorts = 524288 f
    // fco weight copy: past semantic tail (> GGNN gP extent 1,310,720 f)
    short* fcow_b = (short*)(R + 2267408);        // 4194304 shorts = 2097152 f
    // GGNN phase overlays semantic scratch only: gP single [320][4096]
    float* gP     = R;                            // 1,310,720 f

    // ---- dtype detection ----
    detect_dtype<<<1, 256, 0, stream>>>(fc1_w, 4096, flag);

    // ---- all independent prep in ONE dispatch ----
    mega_prep<<<11217, 256, 0, stream>>>(flag, fmap, fc1_w, u5, fco_w,
                                         w3, w4, w5, u3,
                                         fc3_w, fc3_b, fca_w, fca_b,
                                         word, fc2_w,
                                         fmap_b, fc1w_b, u5w_b, wcat_b, fcow_b,
                                         uP, c0, f_wdP);
    reduce_pre<<<81, 256, 0, stream>>>(uP, f_wdP, u, f_wd);

    // ---- semantic stage ----
    mfma_fc1<<<dim3(16, 13), 256, 0, stream>>>(fmap_b, fc1w_b, fh);
    coeff_kernel<<<dim3(NPIX, 4), 256, 0, stream>>>(fh, f_wd, u, c0, s);
    softmax196<<<320, 64, 0, stream>>>(s);
    g_kernel<<<320, 256, 0, stream>>>(s, fmap_b, nodes, nodes_b, g_b);

    // ---- GGNN: 3 time steps (u5 GEMM has fused ew_upd epilogue) ----
    for (int t = 0; t < 3; t++) {
        adj_kernel<<<320, 256, 0, stream>>>(flag, adjm, nodes, a_b);
        mfma_gate<<<dim3(64, 5), 256, 0, stream>>>(a_b, nodes_b, wcat_b, gP);
        ew_r<<<320, 256, 0, stream>>>(flag, gP, nodes, b4, u3b, rn_b, 327680);
        mfma_u5f<<<dim3(16, 5), 256, 0, stream>>>(flag, rn_b, u5w_b, gP,
                                                  b3, u3b, b5, u5b, nodes, nodes_b);
    }

    // ---- output: tanh([nodes|g] @ fco_w.T + fco_b), fused epilogue ----
    mfma_finf<<<dim3(32, 5), 256, 0, stream>>>(flag, nodes_b, g_b, fcow_b, fco_b, d_out);
}

// Round 12
// 395.350 us; speedup vs baseline: 1.0290x; 1.0290x over previous
//
#include <hip/hip_runtime.h>
#include <hip/hip_bf16.h>

#define LL 80
#define NPIX 784
#define PBATCH 15680

#define DI __device__ __forceinline__

typedef short s8v __attribute__((ext_vector_type(8)));     // 8 bf16 = 16B
typedef short short4v __attribute__((ext_vector_type(4))); // 4 bf16 = 8B
typedef float f32x4 __attribute__((ext_vector_type(4)));   // MFMA acc

DI float b2f(__hip_bfloat16 x) { return __bfloat162float(x); }
DI float s2f(short h) { return __uint_as_float(((unsigned int)(unsigned short)h) << 16); }

// f32 -> bf16 bits, round-nearest-even
DI short f2b(float x) {
    unsigned int b = __float_as_uint(x);
    b += 0x7fffu + ((b >> 16) & 1u);
    return (short)(b >> 16);
}

template <int F> DI float LD(const void* p, int i) {
    if (F) return ((const float*)p)[i];
    return b2f(((const __hip_bfloat16*)p)[i]);
}
DI float LDf(int f, const void* p, int i) { return f ? ((const float*)p)[i] : b2f(((const __hip_bfloat16*)p)[i]); }

DI float fast_tanh(float x) {
    float e = __expf(2.0f * x);
    return 1.0f - 2.0f / (e + 1.0f);
}
DI float fast_sigmoid(float x) { return 1.0f / (1.0f + __expf(-x)); }

// ---------------- dtype probe (proven R3-R11) ----------------
__global__ __launch_bounds__(256) void detect_dtype(const void* probe, int n, int* flag) {
    __shared__ int bad;
    if (threadIdx.x == 0) bad = 0;
    __syncthreads();
    int c = 0;
    for (int i = threadIdx.x; i < n; i += 256) {
        float v = b2f(((const __hip_bfloat16*)probe)[i]);
        if (!(fabsf(v) < 1000.0f)) c++;
    }
    if (c) atomicAdd(&bad, c);
    __syncthreads();
    if (threadIdx.x == 0) *flag = (bad > 8) ? 1 : 0;   // 1 => inputs are f32
}

// ---------------- prep sub-parts (unchanged from R11) ----------------
DI void cvt_part(int f, const void* src, short* __restrict__ dst, int blk, int n) {
    int i0 = (blk * 256 + threadIdx.x) * 4;
    if (i0 >= n) return;
    if (f) {
        float4 v = *(const float4*)((const float*)src + i0);
        short4v o = { f2b(v.x), f2b(v.y), f2b(v.z), f2b(v.w) };
        *(short4v*)(dst + i0) = o;
    } else {
        *(short4v*)(dst + i0) = *(const short4v*)((const short*)src + i0);
    }
}

DI void wcat_part(int f, const void* w3, const void* w4, const void* w5, const void* u3,
                  short* __restrict__ wcat, int blk) {
    int i0 = (blk * 256 + threadIdx.x) * 4;
    int nr = i0 >> 10, k = i0 & 1023;
    int j = nr >> 10, r = nr & 1023;
    const void* W = (j == 0) ? w3 : (j == 1) ? w4 : (j == 2) ? w5 : u3;
    float4 v;
    if (j < 3) {
        if (f) {
            float4 x = *(const float4*)((const float*)W + r * 2048 + k);
            float4 y = *(const float4*)((const float*)W + r * 2048 + 1024 + k);
            v.x = x.x + y.x; v.y = x.y + y.y; v.z = x.z + y.z; v.w = x.w + y.w;
        } else {
            const short* Ws = (const short*)W;
            short4v x = *(const short4v*)(Ws + r * 2048 + k);
            short4v y = *(const short4v*)(Ws + r * 2048 + 1024 + k);
            v.x = s2f(x.x) + s2f(y.x); v.y = s2f(x.y) + s2f(y.y);
            v.z = s2f(x.z) + s2f(y.z); v.w = s2f(x.w) + s2f(y.w);
        }
    } else {
        if (f) v = *(const float4*)((const float*)W + r * 1024 + k);
        else {
            short4v x = *(const short4v*)((const short*)W + r * 1024 + k);
            v.x = s2f(x.x); v.y = s2f(x.y); v.z = s2f(x.z); v.w = s2f(x.w);
        }
    }
    short4v o = { f2b(v.x), f2b(v.y), f2b(v.z), f2b(v.w) };
    *(short4v*)(wcat + i0) = o;
}

template <int F>
DI void u_part(const void* fc3_w, const void* fca_w, float* __restrict__ uP, int jsplit) {
    int k4 = threadIdx.x * 4;
    float4 acc = {0.f, 0.f, 0.f, 0.f};
    for (int j = jsplit * 16; j < jsplit * 16 + 16; j++) {
        float fa = LD<F>(fca_w, j);
        float4 row;
        if (F) row = *(const float4*)((const float*)fc3_w + j * 1024 + k4);
        else {
            short4v x = *(const short4v*)((const short*)fc3_w + j * 1024 + k4);
            row.x = s2f(x.x); row.y = s2f(x.y); row.z = s2f(x.z); row.w = s2f(x.w);
        }
        acc.x += fa * row.x; acc.y += fa * row.y;
        acc.z += fa * row.z; acc.w += fa * row.w;
    }
    *(float4*)(uP + jsplit * 1024 + k4) = acc;
}

template <int F>
DI void c0_part(const void* fc3_b, const void* fca_w, const void* fca_b,
                float* c0, float* red) {
    float acc = 0.f;
    for (int j = threadIdx.x; j < 1024; j += 256)
        acc += LD<F>(fc3_b, j) * LD<F>(fca_w, j);
    red[threadIdx.x] = acc;
    __syncthreads();
    for (int s = 128; s > 0; s >>= 1) {
        if (threadIdx.x < s) red[threadIdx.x] += red[threadIdx.x + s];
        __syncthreads();
    }
    if (threadIdx.x == 0) *c0 = red[0] + LD<F>(fca_b, 0);
}

template <int F>
DI void fc2_part(float* lds, const void* word, const void* fc2_w, float* C,
                 int bx, int by, int kb, int ke) {
    float* As = lds;
    float* Ws2 = lds + 1088;
    const int tid = threadIdx.x;
    const int tx = tid & 15, ty = tid >> 4;
    const int m0 = by * 64, n0 = bx * 64;
    const int M = 80;
    float acc[4][4] = {};

    for (int k0 = kb; k0 < ke; k0 += 16) {
#pragma unroll
        for (int i = 0; i < 4; i++) {
            int idx = tid + i * 256;
            int kk = idx & 15, mm = idx >> 4;
            int m = m0 + mm, k = k0 + kk;
            As[kk * 68 + mm] = (m < M && k < ke) ? LD<F>(word, m * 300 + k) : 0.f;
        }
#pragma unroll
        for (int i = 0; i < 4; i++) {
            int idx = tid + i * 256;
            int kk = idx & 15, nn = idx >> 4;
            int n = n0 + nn, k = k0 + kk;
            Ws2[kk * 68 + nn] = (k < ke) ? LD<F>(fc2_w, n * 300 + k) : 0.f;
        }
        __syncthreads();
#pragma unroll
        for (int kk = 0; kk < 16; kk++) {
            float4 av = *(const float4*)(&As[kk * 68 + ty * 4]);
            float4 wv = *(const float4*)(&Ws2[kk * 68 + tx * 4]);
            float a4[4] = {av.x, av.y, av.z, av.w};
            float w4[4] = {wv.x, wv.y, wv.z, wv.w};
#pragma unroll
            for (int i = 0; i < 4; i++)
#pragma unroll
                for (int j = 0; j < 4; j++)
                    acc[i][j] += a4[i] * w4[j];
        }
        __syncthreads();
    }

    for (int i = 0; i < 4; i++) {
        int m = m0 + ty * 4 + i;
        if (m >= M) continue;
        for (int j = 0; j < 4; j++)
            C[m * 1024 + n0 + tx * 4 + j] = acc[i][j];
    }
}

__global__ __launch_bounds__(256) void mega_prep(
    const int* flag,
    const void* fmap, const void* fc1_w, const void* u5w, const void* fco_w,
    const void* w3, const void* w4, const void* w5, const void* u3,
    const void* fc3_w, const void* fc3_b, const void* fca_w, const void* fca_b,
    const void* word, const void* fc2_w,
    short* fmap_b, short* fc1w_b, short* u5w_b, short* wcat_b, short* fcow_b,
    float* uP, float* c0, float* f_wdP) {
    __shared__ float lds[2176];
    int f = *flag;
    int bid = blockIdx.x;
    if (bid < 64) {
        if (f) u_part<1>(fc3_w, fca_w, uP, bid);
        else   u_part<0>(fc3_w, fca_w, uP, bid);
    } else if (bid == 64) {
        if (f) c0_part<1>(fc3_b, fca_w, fca_b, c0, lds);
        else   c0_part<0>(fc3_b, fca_w, fca_b, c0, lds);
    } else if (bid < 193) {
        int r = bid - 65;
        int sp = r >> 5, rr = r & 31;
        int kb = sp * 80, ke = (sp == 3) ? 300 : kb + 80;
        float* C = f_wdP + sp * 81920;
        if (f) fc2_part<1>(lds, word, fc2_w, C, rr & 15, rr >> 4, kb, ke);
        else   fc2_part<0>(lds, word, fc2_w, C, rr & 15, rr >> 4, kb, ke);
    }
    else if (bid < 977)  cvt_part(f, fmap,  fmap_b, bid - 193,  802816);
    else if (bid < 2001) cvt_part(f, fc1_w, fc1w_b, bid - 977,  1048576);
    else if (bid < 3025) cvt_part(f, u5w,   u5w_b,  bid - 2001, 1048576);
    else if (bid < 7121) wcat_part(f, w3, w4, w5, u3, wcat_b, bid - 3025);
    else                 cvt_part(f, fco_w, fcow_b, bid - 7121, 4194304);
}

// ================= bf16 MFMA GEMM core — software-pipelined (proven R10) =================
DI void mcore_b(const short* __restrict__ A, int lda,
                const short* __restrict__ B, int ldb,
                float* __restrict__ C, int ldc,
                int M, int kb, int ke, int m0, int n0) {
    __shared__ short As[4][64][8];
    __shared__ short Ws[4][64][8];
    const int tid = threadIdx.x;
    const int wv = tid >> 6, lane = tid & 63;
    const int mA = tid & 63, qA = tid >> 6;
    const int gm = m0 + mA;
    const int lp = (mA & 15) | (qA << 4), lg = mA >> 4;
    f32x4 acc[4] = {};

    s8v va = {0,0,0,0,0,0,0,0};
    if (gm < M) va = *(const s8v*)(A + gm * lda + kb + 8 * qA);
    s8v vb = *(const s8v*)(B + (n0 + mA) * ldb + kb + 8 * qA);

    for (int k0 = kb; k0 < ke; k0 += 32) {
        *(s8v*)&As[lg][lp][0] = va;
        *(s8v*)&Ws[lg][lp][0] = vb;
        __syncthreads();
        int kn = k0 + 32;
        if (kn < ke) {
            if (gm < M) va = *(const s8v*)(A + gm * lda + kn + 8 * qA);
            vb = *(const s8v*)(B + (n0 + mA) * ldb + kn + 8 * qA);
        }
        s8v af = *(const s8v*)&As[wv][lane][0];
#pragma unroll
        for (int nf = 0; nf < 4; nf++) {
            s8v bf = *(const s8v*)&Ws[nf][lane][0];
            acc[nf] = __builtin_amdgcn_mfma_f32_16x16x32_bf16(af, bf, acc[nf], 0, 0, 0);
        }
        __syncthreads();
    }

    const int q = lane >> 4, cc = lane & 15;
#pragma unroll
    for (int nf = 0; nf < 4; nf++) {
        int n = n0 + 16 * nf + cc;
#pragma unroll
        for (int r = 0; r < 4; r++) {
            int m = m0 + 16 * wv + q * 4 + r;
            if (m < M) C[m * ldc + n] = acc[nf][r];
        }
    }
}

// fc1 (split-K z=2, restored per R11 lesson) + reduce_pre folded into grid tail
__global__ __launch_bounds__(256) void fc1_plus(
    const short* __restrict__ fmap_b, const short* __restrict__ fc1w_b,
    float* __restrict__ fhP,
    const float* __restrict__ uP, const float* __restrict__ f_wdP,
    float* __restrict__ u, float* __restrict__ f_wd,
    const float* __restrict__ c0, float* __restrict__ sc) {
    int bid = blockIdx.x;
    if (bid < 416) {
        int z = bid / 208, rem = bid % 208;
        mcore_b(fmap_b, 1024, fc1w_b, 1024, fhP + z * 802816, 1024,
                NPIX, z * 512, z * 512 + 512, (rem / 16) * 64, (rem % 16) * 64);
    } else if (bid < 496) {
        int i4 = ((bid - 416) * 256 + threadIdx.x) * 4;
        float4 a = *(const float4*)(f_wdP + i4);
        float4 b = *(const float4*)(f_wdP + 81920 + i4);
        float4 c = *(const float4*)(f_wdP + 163840 + i4);
        float4 d = *(const float4*)(f_wdP + 245760 + i4);
        float4 o = {a.x+b.x+c.x+d.x, a.y+b.y+c.y+d.y, a.z+b.z+c.z+d.z, a.w+b.w+c.w+d.w};
        *(float4*)(f_wd + i4) = o;
    } else {
        __shared__ float red[256];
        int t = threadIdx.x;
        int k4 = t * 4;
        float4 acc = {0.f, 0.f, 0.f, 0.f};
        for (int p = 0; p < 64; p++) {
            float4 q = *(const float4*)(uP + p * 1024 + k4);
            acc.x += q.x; acc.y += q.y; acc.z += q.z; acc.w += q.w;
        }
        *(float4*)(u + k4) = acc;
        red[t] = acc.x + acc.y + acc.z + acc.w;
        __syncthreads();
        for (int s2 = 128; s2 > 0; s2 >>= 1) {
            if (t < s2) red[t] += red[t + s2];
            __syncthreads();
        }
        if (t == 0) *sc = red[0] + *c0;   // sumU + c0
    }
}

// nw GEMM: nodes_b @ wcat^T, split-K z=2 (replaces gate; no adj dependency)
__global__ __launch_bounds__(256) void mfma_nw(
    const short* __restrict__ nodes_b, const short* __restrict__ wcat_b,
    float* __restrict__ nwP) {
    int z = blockIdx.z;
    mcore_b(nodes_b, 1024, wcat_b, 1024, nwP + z * 1310720, 4096,
            320, z * 512, z * 512 + 512, blockIdx.y * 64, blockIdx.x * 64);
}

// mix: adjacency-mix of nw (assoc. reorder) + fused rn production.
// grid 192: bid = b*48+ct ; reg=ct>>4: 0 az cols, 1 ar->rn_b, 2 ah cols.
__global__ __launch_bounds__(256) void mix_kernel(
    const int* flag, const void* adjm, const float* __restrict__ nwP,
    const float* __restrict__ nodes, const void* b4, const void* u3b,
    float* __restrict__ gPm, short* __restrict__ rn_b) {
    __shared__ float adjL[6400];      // adj[l][m]
    __shared__ float tile[5120];      // nw-mix source [m][c], 80x64
    __shared__ float t2[5120];        // u3x tile (reg==1 only)
    int bid = blockIdx.x;
    int b = bid / 48, ct = bid % 48;
    int t = threadIdx.x;
    int f = *flag;
    for (int i = t; i < 6400; i += 256) adjL[i] = LDf(f, adjm, i);
    int reg = ct >> 4;
    int cb = (ct & 15) * 64;
    int srcc = reg * 1024 + cb;
    for (int i = t; i < 1280; i += 256) {
        int m = i >> 4, c4 = (i & 15) * 4;
        const float* p0 = nwP + (size_t)(b * 80 + m) * 4096 + srcc + c4;
        float4 x = *(const float4*)p0;
        float4 y = *(const float4*)(p0 + 1310720);
        float4 v = {x.x + y.x, x.y + y.y, x.z + y.z, x.w + y.w};
        *(float4*)&tile[m * 64 + c4] = v;
    }
    if (reg == 1) {
        for (int i = t; i < 1280; i += 256) {
            int m = i >> 4, c4 = (i & 15) * 4;
            const float* p0 = nwP + (size_t)(b * 80 + m) * 4096 + 3072 + cb + c4;
            float4 x = *(const float4*)p0;
            float4 y = *(const float4*)(p0 + 1310720);
            float4 v = {x.x + y.x, x.y + y.y, x.z + y.z, x.w + y.w};
            *(float4*)&t2[m * 64 + c4] = v;
        }
    }
    __syncthreads();
    int wv = t >> 6, lane = t & 63;
    float acc[20];
#pragma unroll
    for (int p = 0; p < 20; p++) acc[p] = 0.f;
    for (int m = 0; m < 80; m++) {
        float tv = tile[m * 64 + lane];
#pragma unroll
        for (int p = 0; p < 20; p++)
            acc[p] += adjL[(wv + 4 * p) * 80 + m] * tv;
    }
    if (reg == 1) {
        int cg = cb + lane;
        float bb = LDf(f, b4, cg) + LDf(f, u3b, cg);
#pragma unroll
        for (int p = 0; p < 20; p++) {
            int l = wv + 4 * p;
            int bl = b * 80 + l;
            float r = fast_sigmoid(acc[p] + t2[l * 64 + lane] + bb);
            rn_b[bl * 1024 + cg] = f2b(r * nodes[bl * 1024 + cg]);
        }
    } else {
        int off = (reg == 0) ? 0 : 1024;
#pragma unroll
        for (int p = 0; p < 20; p++) {
            int bl = b * 80 + wv + 4 * p;
            gPm[bl * 2048 + off + cb + lane] = acc[p];
        }
    }
}

// u5 GEMM with FUSED ew_upd epilogue, pipelined (K=1024). Reads gPm + nw u3x cols.
__global__ __launch_bounds__(256) void mfma_u5f(
    const int* flag, const short* __restrict__ rn_b, const short* __restrict__ u5w_b,
    const float* __restrict__ gPm, const float* __restrict__ nwP,
    const void* b3, const void* u3b, const void* b5, const void* u5b,
    float* __restrict__ nodes, short* __restrict__ nodes_b) {
    __shared__ short As[4][64][8];
    __shared__ short Ws[4][64][8];
    const int tid = threadIdx.x;
    const int wv = tid >> 6, lane = tid & 63;
    const int mA = tid & 63, qA = tid >> 6;
    const int lp = (mA & 15) | (qA << 4), lg = mA >> 4;
    const int m0 = blockIdx.y * 64, n0 = blockIdx.x * 64;
    f32x4 acc[4] = {};

    s8v va = *(const s8v*)(rn_b + (m0 + mA) * 1024 + 8 * qA);
    s8v vb = *(const s8v*)(u5w_b + (n0 + mA) * 1024 + 8 * qA);

    for (int k0 = 0; k0 < 1024; k0 += 32) {
        *(s8v*)&As[lg][lp][0] = va;
        *(s8v*)&Ws[lg][lp][0] = vb;
        __syncthreads();
        int kn = k0 + 32;
        if (kn < 1024) {
            va = *(const s8v*)(rn_b + (m0 + mA) * 1024 + kn + 8 * qA);
            vb = *(const s8v*)(u5w_b + (n0 + mA) * 1024 + kn + 8 * qA);
        }
        s8v af = *(const s8v*)&As[wv][lane][0];
#pragma unroll
        for (int nf = 0; nf < 4; nf++) {
            s8v bf = *(const s8v*)&Ws[nf][lane][0];
            acc[nf] = __builtin_amdgcn_mfma_f32_16x16x32_bf16(af, bf, acc[nf], 0, 0, 0);
        }
        __syncthreads();
    }

    const int f = *flag;
    const int q = lane >> 4, cc = lane & 15;
#pragma unroll
    for (int nf = 0; nf < 4; nf++) {
        int n = n0 + 16 * nf + cc;
        float bb3 = LDf(f, b3, n) + LDf(f, u3b, n);
        float bb5 = LDf(f, b5, n) + LDf(f, u5b, n);
#pragma unroll
        for (int r = 0; r < 4; r++) {
            int m = m0 + 16 * wv + q * 4 + r;
            int i = m * 1024 + n;
            float az = gPm[m * 2048 + n];
            float ah = gPm[m * 2048 + 1024 + n];
            const float* up = nwP + (size_t)m * 4096 + 3072 + n;
            float ux = up[0] + up[1310720];
            float z = fast_sigmoid(az + ux + bb3);
            float h = fast_tanh(ah + acc[nf][r] + bb5);
            float nd = (1.f - z) * nodes[i] + z * h;
            nodes[i] = nd;
            nodes_b[i] = f2b(nd);
        }
    }
}

// final GEMM with FUSED bias+tanh+store, pipelined (proven R10).
__global__ __launch_bounds__(256) void mfma_finf(
    const int* flag, const short* __restrict__ nodes_b, const short* __restrict__ g_b,
    const short* __restrict__ fcow_b, const void* fco_b, void* out) {
    __shared__ short As[4][64][8];
    __shared__ short Ws[4][64][8];
    const int tid = threadIdx.x;
    const int wv = tid >> 6, lane = tid & 63;
    const int mA = tid & 63, qA = tid >> 6;
    const int lp = (mA & 15) | (qA << 4), lg = mA >> 4;
    const int m0 = blockIdx.y * 64, n0 = blockIdx.x * 64;
    f32x4 acc[4] = {};

    s8v va = *(const s8v*)(nodes_b + (m0 + mA) * 1024 + 8 * qA);
    s8v vb = *(const s8v*)(fcow_b + (n0 + mA) * 2048 + 8 * qA);

    for (int k0 = 0; k0 < 2048; k0 += 32) {
        *(s8v*)&As[lg][lp][0] = va;
        *(s8v*)&Ws[lg][lp][0] = vb;
        __syncthreads();
        int kn = k0 + 32;
        if (kn < 2048) {
            const short* Apn = (kn < 1024) ? nodes_b : (g_b - 1024);
            va = *(const s8v*)(Apn + (m0 + mA) * 1024 + kn + 8 * qA);
            vb = *(const s8v*)(fcow_b + (n0 + mA) * 2048 + kn + 8 * qA);
        }
        s8v af = *(const s8v*)&As[wv][lane][0];
#pragma unroll
        for (int nf = 0; nf < 4; nf++) {
            s8v bf = *(const s8v*)&Ws[nf][lane][0];
            acc[nf] = __builtin_amdgcn_mfma_f32_16x16x32_bf16(af, bf, acc[nf], 0, 0, 0);
        }
        __syncthreads();
    }

    const int f = *flag;
    const int q = lane >> 4, cc = lane & 15;
#pragma unroll
    for (int nf = 0; nf < 4; nf++) {
        int n = n0 + 16 * nf + cc;
        float bias = LDf(f, fco_b, n);
#pragma unroll
        for (int r = 0; r < 4; r++) {
            int m = m0 + 16 * wv + q * 4 + r;
            float v = fast_tanh(acc[nf][r] + bias);
            if (f) ((float*)out)[m * 2048 + n] = v;
            else   ((__hip_bfloat16*)out)[m * 2048 + n] = __float2bfloat16(v);
        }
    }
}

// ---------------- coeff: algebraic refactor — s = sc − 2·Σ u_k/(e^{2·fh·fd}+1) ----------------
__global__ __launch_bounds__(256) void coeff_kernel(
    const float* __restrict__ fhP, const float* __restrict__ f_wd,
    const float* __restrict__ u, const float* __restrict__ scp,
    float* __restrict__ s) {
    int n = blockIdx.x;  // 0..783
    __shared__ float4 fh4[256];   // 2*fh (partials summed)
    __shared__ float4 uu4[256];
    int t = threadIdx.x;
    {
        float4 a0 = *(const float4*)(fhP + n * 1024 + t * 4);
        float4 a1 = *(const float4*)(fhP + 802816 + n * 1024 + t * 4);
        float4 fv = {2.f*(a0.x + a1.x), 2.f*(a0.y + a1.y), 2.f*(a0.z + a1.z), 2.f*(a0.w + a1.w)};
        fh4[t] = fv;
        uu4[t] = *(const float4*)(u + t * 4);
    }
    __syncthreads();
    float sc = *scp;
    int wave = t >> 6, lane = t & 63;
    int b = n / 196, hw = n % 196;
    int l0 = blockIdx.y * 20;
    for (int l = l0 + wave; l < l0 + 20; l += 4) {
        const float4* fd4 = (const float4*)(f_wd + l * 1024);
        float p = 0.f;
#pragma unroll
        for (int k = 0; k < 4; k++) {
            int idx = lane + k * 64;
            float4 h = fh4[idx];
            float4 d = fd4[idx];
            float4 uu = uu4[idx];
            p += uu.x * __builtin_amdgcn_rcpf(__expf(h.x * d.x) + 1.f);
            p += uu.y * __builtin_amdgcn_rcpf(__expf(h.y * d.y) + 1.f);
            p += uu.z * __builtin_amdgcn_rcpf(__expf(h.z * d.z) + 1.f);
            p += uu.w * __builtin_amdgcn_rcpf(__expf(h.w * d.w) + 1.f);
        }
        for (int off = 32; off > 0; off >>= 1) p += __shfl_down(p, off);
        if (lane == 0) s[b * PBATCH + hw * LL + l] = sc - 2.f * p;
    }
}

// ---------------- softmax over contiguous 196-chunks ----------------
__global__ __launch_bounds__(64) void softmax196(float* __restrict__ s) {
    float* p = s + blockIdx.x * 196;
    int lane = threadIdx.x;
    float v[4];
    float mx = -1e30f;
#pragma unroll
    for (int i = 0; i < 4; i++) {
        int idx = lane + i * 64;
        v[i] = (idx < 196) ? p[idx] : -1e30f;
        mx = fmaxf(mx, v[i]);
    }
    for (int off = 32; off > 0; off >>= 1) mx = fmaxf(mx, __shfl_down(mx, off));
    mx = __shfl(mx, 0);
    float sum = 0.f;
#pragma unroll
    for (int i = 0; i < 4; i++) {
        int idx = lane + i * 64;
        if (idx < 196) { v[i] = __expf(v[i] - mx); sum += v[i]; }
    }
    for (int off = 32; off > 0; off >>= 1) sum += __shfl_down(sum, off);
    sum = __shfl(sum, 0);
    float inv = 1.f / sum;
#pragma unroll
    for (int i = 0; i < 4; i++) {
        int idx = lane + i * 64;
        if (idx < 196) p[idx] = v[i] * inv;
    }
}

// ---------------- g: reads bf16 fmap_b, 4 c per thread ----------------
__global__ __launch_bounds__(256) void g_kernel(
    const float* __restrict__ s, const short* __restrict__ fmap_b,
    float* __restrict__ nodes, short* __restrict__ nodes_b, short* __restrict__ g_b) {
    int bl = blockIdx.x;
    int b = bl / LL, l = bl % LL;
    __shared__ float co[196];
    for (int i = threadIdx.x; i < 196; i += 256)
        co[i] = s[b * PBATCH + i * LL + l];
    __syncthreads();
    int c4 = threadIdx.x * 4;
    const short* base = fmap_b + b * 196 * 1024 + c4;
    float a0 = 0.f, a1 = 0.f, a2 = 0.f, a3 = 0.f;
    for (int hw = 0; hw < 196; hw++) {
        short4v v = *(const short4v*)(base + hw * 1024);
        float w = co[hw];
        a0 += w * s2f(v.x); a1 += w * s2f(v.y);
        a2 += w * s2f(v.z); a3 += w * s2f(v.w);
    }
    int o = bl * 1024 + c4;
    float4 fa = {a0, a1, a2, a3};
    *(float4*)(nodes + o) = fa;
    short4v bb = { f2b(a0), f2b(a1), f2b(a2), f2b(a3) };
    *(short4v*)(nodes_b + o) = bb;
    *(short4v*)(g_b + o) = bb;
}

extern "C" void kernel_launch(void* const* d_in, const int* in_sizes, int n_in,
                              void* d_out, int out_size, void* d_ws, size_t ws_size,
                              hipStream_t stream) {
    const void* fmap  = d_in[0];
    const void* word  = d_in[1];
    const void* adjm  = d_in[2];
    const void* fc1_w = d_in[3];
    const void* fc2_w = d_in[4];
    const void* fc3_w = d_in[5];
    const void* fc3_b = d_in[6];
    const void* fca_w = d_in[7];
    const void* fca_b = d_in[8];
    const void* w3    = d_in[9];
    const void* b3    = d_in[10];
    const void* u3    = d_in[11];
    const void* u3b   = d_in[12];
    const void* w4    = d_in[13];
    const void* b4    = d_in[14];
    const void* w5    = d_in[15];
    const void* b5    = d_in[16];
    const void* u5    = d_in[17];
    const void* u5b   = d_in[18];
    const void* fco_w = d_in[19];
    const void* fco_b = d_in[20];

    // ---- workspace: increments in FLOATS (bf16 buffers = elems/2). ~35.3 MB
    // (R9 passed at 35.1 MB — same class). All offsets re-audited.
    int*   flag    = (int*)d_ws;
    float* P       = (float*)d_ws + 16;
    float* nodes   = P;                       P += 327680;   // f32, persistent
    short* nodes_b = (short*)P;               P += 163840;   // 327680 bf16
    short* g_b     = (short*)P;               P += 163840;   // 327680 bf16
    short* rn_b    = (short*)P;               P += 163840;   // 327680 bf16
    short* u5w_b   = (short*)P;               P += 524288;   // 1048576 bf16
    short* wcat_b  = (short*)P;               P += 2097152;  // 4096x1024 bf16
    float* R       = P;                                      // overlay region
    // semantic phase (extent 3,070,240 f)
    float* fhP    = R;                            // 2 x 802816
    float* f_wd   = R + 1605632;                  // 81920
    float* f_wdP  = f_wd + 81920;                 // 4 x 81920
    float* uP     = f_wdP + 327680;               // 64 x 1024
    float* u      = uP + 65536;                   // 1024
    float* c0     = u + 1024;                     // 16
    float* sc     = c0 + 16;                      // 16
    float* s      = sc + 16;                      // 62720
    short* fmap_b = (short*)(s + 62720);          // 802816 shorts = 401408 f
    short* fc1w_b = (short*)(s + 62720 + 401408); // 1048576 shorts = 524288 f
    // GGNN phase overlays semantic (extent 3,276,800 f)
    float* nwP    = R;                            // 2 x 1310720
    float* gPm    = R + 2621440;                  // 320 x 2048 = 655360
    // fco weight copy: past max(semantic, GGNN) extent
    short* fcow_b = (short*)(R + 3276800);        // 4194304 shorts = 2097152 f

    // ---- dtype detection ----
    detect_dtype<<<1, 256, 0, stream>>>(fc1_w, 4096, flag);

    // ---- all independent prep in ONE dispatch ----
    mega_prep<<<11217, 256, 0, stream>>>(flag, fmap, fc1_w, u5, fco_w,
                                         w3, w4, w5, u3,
                                         fc3_w, fc3_b, fca_w, fca_b,
                                         word, fc2_w,
                                         fmap_b, fc1w_b, u5w_b, wcat_b, fcow_b,
                                         uP, c0, f_wdP);

    // ---- semantic stage: fc1 (split-K z=2) + reduce folded into one dispatch ----
    fc1_plus<<<497, 256, 0, stream>>>(fmap_b, fc1w_b, fhP, uP, f_wdP, u, f_wd, c0, sc);
    coeff_kernel<<<dim3(NPIX, 4), 256, 0, stream>>>(fhP, f_wd, u, sc, s);
    softmax196<<<320, 64, 0, stream>>>(s);
    g_kernel<<<320, 256, 0, stream>>>(s, fmap_b, nodes, nodes_b, g_b);

    // ---- GGNN: 3 time steps, 3 dispatches each (assoc. reorder kills adj+ew_r) ----
    for (int t = 0; t < 3; t++) {
        mfma_nw<<<dim3(64, 5, 2), 256, 0, stream>>>(nodes_b, wcat_b, nwP);
        mix_kernel<<<192, 256, 0, stream>>>(flag, adjm, nwP, nodes, b4, u3b, gPm, rn_b);
        mfma_u5f<<<dim3(16, 5), 256, 0, stream>>>(flag, rn_b, u5w_b, gPm, nwP,
                                                  b3, u3b, b5, u5b, nodes, nodes_b);
    }

    // ---- output: tanh([nodes|g] @ fco_w.T + fco_b), fused epilogue ----
    mfma_finf<<<dim3(32, 5), 256, 0, stream>>>(flag, nodes_b, g_b, fcow_b, fco_b, d_out);
}